// Round 1
// baseline (83.857 us; speedup 1.0000x reference)
//
#include <hip/hip_runtime.h>

// Polyphase resample up=3 down=2, N=2097152, L=129 taps, start=(L-1)/2=64.
// out[3j+0] = 3 * sum_i x[21+2j-i] * h[1+3i]   (i in [0,43))
// out[3j+1] = 3 * sum_i x[22+2j-i] * h[0+3i]
// out[3j+2] = 3 * sum_i x[22+2j-i] * h[2+3i]
// Out-of-range x indices are zero (zero-stuffed conv boundary).

#define N_SIG   2097152
#define L_FILT  129
#define NTAPS   43          // taps per phase
#define G       8           // output groups per thread
#define BLK     256
#define GROUPS_PER_BLK (BLK * G)            // 2048 groups -> 6144 outputs/block
#define TILE_Q  4160                        // unpadded tile floats (multiple of 4)
#define TILE_P  (TILE_Q + (TILE_Q / 16) * 4) // 5200 padded (4 pad words per 16)

__global__ __launch_bounds__(BLK) void poly_kernel(
    const float* __restrict__ x, const float* __restrict__ h,
    float* __restrict__ out, int n_out)
{
    __shared__ float xs[TILE_P];
    __shared__ float hs[L_FILT];

    const int tid = threadIdx.x;
    const int b   = blockIdx.x;

    // Stage filter taps, folding in the gain `up`=3 once.
    if (tid < L_FILT) hs[tid] = 3.0f * h[tid];

    // x-tile base (x index of logical tile word q=0), 4-float aligned.
    // First thread's window starts at x[2*j0 - 21] = x[4096*b - 21]; we
    // align down to 4096*b - 24, so windows sit at logical word 16*tid + 3.
    const int tb = 4096 * b - 24;

    // Coalesced staging with zero-pad at array edges.
    // Padded layout: logical word q lives at q + 4*(q>>4)  (keeps every
    // float4 contiguous; window reads get lane-stride 20 words -> all 32
    // banks covered, conflict-free).
    for (int q4 = tid; q4 < TILE_Q / 4; q4 += BLK) {
        const int gx = tb + 4 * q4;
        float4 v;
        if (gx >= 0 && gx + 3 < N_SIG) {
            v = *(const float4*)(x + gx);
        } else {
            v.x = (gx     >= 0 && gx     < N_SIG) ? x[gx]     : 0.0f;
            v.y = (gx + 1 >= 0 && gx + 1 < N_SIG) ? x[gx + 1] : 0.0f;
            v.z = (gx + 2 >= 0 && gx + 2 < N_SIG) ? x[gx + 2] : 0.0f;
            v.w = (gx + 3 >= 0 && gx + 3 < N_SIG) ? x[gx + 3] : 0.0f;
        }
        const int p = 4 * q4 + 4 * (q4 >> 2);
        *(float4*)(xs + p) = v;
    }
    __syncthreads();

    // Register window: logical words [16*tid, 16*tid+64) of the tile,
    // i.e. x[tb + 16*tid + d] = w[d]. Needed range d in [3, 60].
    float w[64];
#pragma unroll
    for (int k = 0; k < 16; ++k) {
        const int p = 20 * tid + 4 * k + 4 * (k >> 2);
        const float4 v = *(const float4*)(xs + p);
        w[4 * k + 0] = v.x; w[4 * k + 1] = v.y;
        w[4 * k + 2] = v.z; w[4 * k + 3] = v.w;
    }

    float acc[3 * G];
#pragma unroll
    for (int k = 0; k < 3 * G; ++k) acc[k] = 0.0f;

    // Thread handles groups j = 2048*b + 8*tid + g, g in [0,8).
    // x[21+2j-i] -> w[45 + 2g - i], x[22+2j-i] -> w[46 + 2g - i].
#pragma unroll
    for (int i = 0; i < NTAPS; ++i) {
        const float h0 = hs[3 * i + 0];
        const float h1 = hs[3 * i + 1];
        const float h2 = hs[3 * i + 2];
#pragma unroll
        for (int g = 0; g < G; ++g) {
            const float xa = w[45 + 2 * g - i];
            const float xb = w[46 + 2 * g - i];
            acc[3 * g + 0] += xa * h1;
            acc[3 * g + 1] += xb * h0;
            acc[3 * g + 2] += xb * h2;
        }
    }

    // 24 contiguous outputs per thread, 16B-aligned.
    const long ob = (long)GROUPS_PER_BLK * b * 3 + (long)(3 * G) * tid;
#pragma unroll
    for (int k = 0; k < 6; ++k) {
        if (ob + 4 * k + 3 < (long)n_out) {
            *(float4*)(out + ob + 4 * k) =
                make_float4(acc[4 * k + 0], acc[4 * k + 1],
                            acc[4 * k + 2], acc[4 * k + 3]);
        }
    }
}

extern "C" void kernel_launch(void* const* d_in, const int* in_sizes, int n_in,
                              void* d_out, int out_size, void* d_ws, size_t ws_size,
                              hipStream_t stream) {
    const float* x = (const float*)d_in[0];
    const float* h = (const float*)d_in[1];
    float* out = (float*)d_out;
    const int blocks = (out_size + 3 * GROUPS_PER_BLK - 1) / (3 * GROUPS_PER_BLK);
    poly_kernel<<<blocks, BLK, 0, stream>>>(x, h, out, out_size);
}